// Round 11
// baseline (153.366 us; speedup 1.0000x reference)
//
#include <hip/hip_runtime.h>
#include <hip/hip_bf16.h>

// B=16, S=512, N=64, H=768, E_TYPES=9, R_TYPES=10
// out: entity_logits (73728) | entity_repr (786432) | relation_logits (322560), fp32

#define S_LEN 512
#define H_DIM 768
#define NPAIR 2016

typedef __bf16 bf16x8 __attribute__((ext_vector_type(8)));
typedef float f32x4 __attribute__((ext_vector_type(4)));

__device__ __forceinline__ void gload_lds16(const void* g, void* l) {
    __builtin_amdgcn_global_load_lds(
        (const __attribute__((address_space(1))) void*)g,
        (__attribute__((address_space(3))) void*)l, 16, 0, 0);
}

__device__ __forceinline__ ushort f2bf(float x) {
    __hip_bfloat16 h = __float2bfloat16(x);
    return *(ushort*)&h;
}

// 8 bf16 (16B, aligned) -> 8 f32 via bit ops (exact)
__device__ __forceinline__ void bf8_to_f32(const ushort* p, float* f) {
    const uint* u = (const uint*)p;
    #pragma unroll
    for (int i = 0; i < 4; ++i) {
        uint x = u[i];
        f[2 * i]     = __uint_as_float(x << 16);
        f[2 * i + 1] = __uint_as_float(x & 0xffff0000u);
    }
}

// ---------------------------------------------------------------------------
// K_A: mega prep kernel. blockIdx ranges:
//   [0,1024)      span mean -> erep (fp32) + erep_bf
//   [1024,1312)   trcast W1e (768x384)
//   [1312,1888)   trcast W1r top half (768x768)
//   [1888,2464)   trcast W1r bottom half (768x768)
//   [2464,2542)   W2rt (16x768, pad) + W2et (16x384, pad) + b1r_ext (1536)
// (seq cast job deleted: K1 now stages f32 seq directly)
// ---------------------------------------------------------------------------
__global__ __launch_bounds__(256) void prep_all_k(
    const float* __restrict__ seq, const int* __restrict__ spans,
    const float* __restrict__ W1e, const float* __restrict__ W1r,
    const float* __restrict__ W2e, const float* __restrict__ W2r,
    const float* __restrict__ b1r,
    float* __restrict__ erep, ushort* __restrict__ erep_bf,
    ushort* __restrict__ W1et, ushort* __restrict__ W1rt,
    ushort* __restrict__ W2et, ushort* __restrict__ W2rt,
    float* __restrict__ b1r_ext)
{
    __shared__ float t[32][33];
    const int bid = blockIdx.x, tid = threadIdx.x;

    if (bid < 1024) {
        // ---- span mean ----
        const int bn = bid, b = bn >> 6;
        const int s0 = spans[bn * 2], s1 = spans[bn * 2 + 1];
        int lo = s0 < 0 ? 0 : s0;
        int hi = s1 > S_LEN ? S_LEN : s1;
        int cnt = hi - lo;
        if (cnt < 1) cnt = 1;
        const float inv = 1.f / (float)cnt;
        for (int c = tid; c < H_DIM; c += 256) {
            float acc = 0.f;
            for (int s = lo; s < hi; ++s)
                acc += seq[((size_t)b * S_LEN + s) * H_DIM + c];
            float v = acc * inv;
            erep[(size_t)bn * H_DIM + c] = v;
            erep_bf[(size_t)bn * H_DIM + c] = f2bf(v);
        }
    } else if (bid < 2464) {
        // ---- transpose+cast jobs ----
        const float* src; ushort* dst; int b2, C;
        if (bid < 1312)      { b2 = bid - 1024; src = W1e; dst = W1et; C = 384; }
        else if (bid < 1888) { b2 = bid - 1312; src = W1r; dst = W1rt; C = 768; }
        else                 { b2 = bid - 1888; src = W1r + 768 * 768; dst = W1rt + 768 * 768; C = 768; }
        const int br = b2 % 24, bc = b2 / 24;   // R=768 always -> TR=24
        const int r = tid >> 5, c = tid & 31;
        #pragma unroll
        for (int p = 0; p < 4; ++p) {
            int rr = r + p * 8;
            t[rr][c] = src[(size_t)(br * 32 + rr) * C + bc * 32 + c];
        }
        __syncthreads();
        #pragma unroll
        for (int p = 0; p < 4; ++p) {
            int rr = r + p * 8;
            dst[(size_t)(bc * 32 + rr) * 768 + br * 32 + c] = f2bf(t[c][rr]);
        }
    } else {
        // ---- small weights ----
        int idx = (bid - 2464) * 256 + tid;     // [0, 19968)
        if (idx < 12288) {                       // W2rt[16][768]
            int col = idx / 768, k = idx % 768;
            W2rt[idx] = (col < 10) ? f2bf(W2r[k * 10 + col]) : (ushort)0;
        } else if (idx < 18432) {                // W2et[16][384]
            int u = idx - 12288;
            int col = u / 384, k = u % 384;
            W2et[u] = (col < 9) ? f2bf(W2e[k * 9 + col]) : (ushort)0;
        } else if (idx < 19968) {                // b1r_ext[1536]
            int u = idx - 18432;
            b1r_ext[u] = (u < 768) ? b1r[u] : 0.f;
        }
    }
}

// ---------------------------------------------------------------------------
// GEMM body: C = A[M,K] @ Bt[N,K]^T, tile 64x128, BK=32, 4 waves (2x2),
// wave tile 32x64 (2x4 frags 16x16x32). 4-deep counted-vmcnt pipeline.
// Chunk-XOR swizzle (both-sides): LDS dest linear (gload_lds constraint),
// global SOURCE chunk pre-permuted, frag read applies same XOR ->
// 2-way banks (free) instead of 8/16-way.
//   bf16 tiles: [row][32k], 4 chunks/row,  q ^= (row>>1)&3
//   f32 A tile: [row][32k], 8 chunks/row,  q ^= row&7  (K1 stages seq f32,
//   converts to bf16 at frag build — identical rounding to a pre-cast pass)
// EPI 0: bf16 out = relu(acc + bias[n]);  EPI 2: bf16 out = acc + bias[n].
// ---------------------------------------------------------------------------
template<int EPI, bool AF32>
__device__ __forceinline__ void gemm_body(
    const void* __restrict__ Ap, const ushort* __restrict__ Bt,
    const float* __restrict__ bias, void* __restrict__ Cout,
    int bx, int by, int N, int K, char* As, char* Bs)
{
    const int tid = threadIdx.x;
    const int lane = tid & 63, wid = tid >> 6;
    const int wr = wid >> 1, wc = wid & 1;
    const int m0 = by * 64, n0 = bx * 128;
    const int fr = lane & 15, kg = lane >> 4;

    constexpr int ABUF = AF32 ? 8192 : 4096;   // bytes per A buffer

    // ---- staging source pointers (chunk-swizzled globals) ----
    const int sB_row = tid >> 2;
    const int sB_q   = (tid & 3) ^ ((sB_row >> 1) & 3);
    const ushort* bg0 = Bt + (size_t)(n0 + sB_row) * K + sB_q * 8;
    const ushort* bg1 = bg0 + (size_t)64 * K;
    const ushort* ag16 = nullptr;
    const float *agA = nullptr, *agB = nullptr;
    if constexpr (AF32) {
        const int r = tid >> 3, q = (tid & 7) ^ ((tid >> 3) & 7);
        agA = (const float*)Ap + (size_t)(m0 + r) * K + q * 4;
        agB = agA + (size_t)32 * K;
    } else {
        ag16 = (const ushort*)Ap + (size_t)(m0 + sB_row) * K + sB_q * 8;
    }

    // ---- frag-read byte offsets (constant per lane, swizzled) ----
    int aoff0[2], aoff1[2], boffs[4];
    #pragma unroll
    for (int i = 0; i < 2; ++i) {
        const int row = wr * 32 + i * 16 + fr;
        if constexpr (AF32) {
            aoff0[i] = row * 128 + (((2 * kg)     ^ (row & 7)) * 16);
            aoff1[i] = row * 128 + (((2 * kg + 1) ^ (row & 7)) * 16);
        } else {
            aoff0[i] = row * 64 + ((kg ^ ((row >> 1) & 3)) * 16);
        }
    }
    #pragma unroll
    for (int i = 0; i < 4; ++i) {
        const int col = wc * 64 + i * 16 + fr;
        boffs[i] = col * 64 + ((kg ^ ((col >> 1) & 3)) * 16);
    }

    const int nsteps = K / 32;

    auto STAGE = [&](int kt, int buf) {
        const int kn = kt * 32;   // element offset (f32 or bf16)
        if constexpr (AF32) {
            gload_lds16(agA + kn, As + buf * ABUF + tid * 16);
            gload_lds16(agB + kn, As + buf * ABUF + 4096 + tid * 16);
        } else {
            gload_lds16(ag16 + kn, As + buf * ABUF + tid * 16);
        }
        gload_lds16(bg0 + kn, Bs + buf * 8192 + tid * 16);
        gload_lds16(bg1 + kn, Bs + buf * 8192 + 4096 + tid * 16);
    };

    // prologue: tiles 0,1,2 in flight
    STAGE(0, 0);
    STAGE(1, 1);
    STAGE(2, 2);

    f32x4 acc[2][4] = {};

    for (int t = 0; t < nsteps; ++t) {
        if (t < nsteps - 2) {
            if constexpr (AF32) asm volatile("s_waitcnt vmcnt(8)" ::: "memory");
            else                asm volatile("s_waitcnt vmcnt(6)" ::: "memory");
        } else if (t == nsteps - 2) {
            if constexpr (AF32) asm volatile("s_waitcnt vmcnt(4)" ::: "memory");
            else                asm volatile("s_waitcnt vmcnt(3)" ::: "memory");
        } else {
            asm volatile("s_waitcnt vmcnt(0)" ::: "memory");
        }
        __builtin_amdgcn_s_barrier();          // raw: no implicit vmcnt drain
        __builtin_amdgcn_sched_barrier(0);     // fence: nothing hoists above
        if (t + 3 < nsteps) STAGE(t + 3, (t + 3) & 3);
        const int buf = t & 3;
        bf16x8 af[2], bv[4];
        #pragma unroll
        for (int i = 0; i < 2; ++i) {
            if constexpr (AF32) {
                f32x4 x0 = *(const f32x4*)(As + buf * ABUF + aoff0[i]);
                f32x4 x1 = *(const f32x4*)(As + buf * ABUF + aoff1[i]);
                ushort h[8] __attribute__((aligned(16))) =
                    { f2bf(x0[0]), f2bf(x0[1]), f2bf(x0[2]), f2bf(x0[3]),
                      f2bf(x1[0]), f2bf(x1[1]), f2bf(x1[2]), f2bf(x1[3]) };
                af[i] = *(bf16x8*)h;
            } else {
                af[i] = *(const bf16x8*)(As + buf * ABUF + aoff0[i]);
            }
        }
        #pragma unroll
        for (int i = 0; i < 4; ++i)
            bv[i] = *(const bf16x8*)(Bs + buf * 8192 + boffs[i]);
        #pragma unroll
        for (int mi = 0; mi < 2; ++mi)
            #pragma unroll
            for (int nj = 0; nj < 4; ++nj)
                acc[mi][nj] = __builtin_amdgcn_mfma_f32_16x16x32_bf16(
                    af[mi], bv[nj], acc[mi][nj], 0, 0, 0);
    }

    // C/D: col = lane&15, row = (lane>>4)*4 + reg
    __hip_bfloat16* Cb = (__hip_bfloat16*)Cout;
    float bcol[4];
    #pragma unroll
    for (int nj = 0; nj < 4; ++nj) bcol[nj] = bias[n0 + wc * 64 + nj * 16 + fr];
    #pragma unroll
    for (int mi = 0; mi < 2; ++mi)
        #pragma unroll
        for (int j = 0; j < 4; ++j) {
            size_t rb = (size_t)(m0 + wr * 32 + mi * 16 + kg * 4 + j) * N
                      + n0 + wc * 64 + fr;
            #pragma unroll
            for (int nj = 0; nj < 4; ++nj) {
                float v = acc[mi][nj][j] + bcol[nj];
                if (EPI == 0) v = fmaxf(v, 0.f);
                Cb[rb + nj * 16] = __float2bfloat16(v);
            }
        }
}

// ---------------------------------------------------------------------------
// K_B: fused independent GEMMs in one launch.
//   bid [0,384):   H1bf = relu(seq @ W1et^T + b1e)           (8192x384x768,
//                  A staged as f32 straight from seq — no cast pass)
//   bid [384,576): UVbf = erep_bf @ W1rt^T + b1r_ext (bf16)  (1024x1536x768)
// ---------------------------------------------------------------------------
__global__ __launch_bounds__(256) void gemm2_k(
    const float* __restrict__ seq, const ushort* __restrict__ W1et,
    const float* __restrict__ b1e, ushort* __restrict__ H1bf,
    const ushort* __restrict__ erep_bf, const ushort* __restrict__ W1rt,
    const float* __restrict__ b1r_ext, ushort* __restrict__ UVbf)
{
    __shared__ char As[4 * 8192];   // 32 KB (f32 A for K1; bf16 A uses 16 KB)
    __shared__ char Bs[4 * 8192];   // 32 KB
    const int bid = blockIdx.x;
    if (bid < 384) {
        gemm_body<0, true>(seq, W1et, b1e, H1bf, bid % 3, bid / 3, 384, 768, As, Bs);
    } else {
        const int b2 = bid - 384;
        gemm_body<2, false>(erep_bf, W1rt, b1r_ext, UVbf, b2 % 12, b2 / 12, 1536, 768, As, Bs);
    }
}

// ---------------------------------------------------------------------------
// K_C: fused consumers in one launch.
//   bid [0,160):   relation logits per (batch, 16x16 pair tile): barrier-free,
//                  LDS-free. U reads wave-uniform (broadcast), V reads 16 rows
//                  x one 64B line per chunk. hidden = relu(Ubf + Vbf) (bias
//                  pre-folded into U), MFMA vs W2rt, direct store + b2r.
//   bid [160,288): entity_logits = H1bf @ W2et^T + b2e (barrier-free MFMA)
// ---------------------------------------------------------------------------
__global__ __launch_bounds__(256) void post_k(
    const ushort* __restrict__ UVbf, const ushort* __restrict__ W2rt,
    const float* __restrict__ b2r, float* __restrict__ rlog,
    const ushort* __restrict__ H1, const ushort* __restrict__ W2et,
    const float* __restrict__ b2e, float* __restrict__ elog)
{
    const int tid = threadIdx.x;
    const int lane = tid & 63, wid = tid >> 6;
    const int fr = lane & 15, kg = lane >> 4;
    const int bid = blockIdx.x;

    if (bid < 160) {
        // ---- relation logits, one (batch, i-tile, j-tile) per block ----
        const int t = bid % 10, b = bid / 10;
        int it, jt;
        if (t < 4)      { it = 0; jt = t; }
        else if (t < 7) { it = 1; jt = t - 3; }
        else if (t < 9) { it = 2; jt = t - 5; }
        else            { it = 3; jt = 3; }
        const int i0 = it * 16, j0 = jt * 16;
        const ushort* Ub = UVbf + (size_t)(b * 64 + i0) * 1536;         // U rows
        const ushort* Vb = UVbf + (size_t)(b * 64 + j0) * 1536 + 768;   // V rows

        f32x4 acc[4] = {};

        for (int c = 0; c < 24; ++c) {
            const int kk = c * 32 + kg * 8;
            const bf16x8 bv = *(const bf16x8*)(W2rt + fr * 768 + kk);
            float fv[8];
            bf8_to_f32(Vb + (size_t)fr * 1536 + kk, fv);   // jj = fr (A-frag row)
            #pragma unroll
            for (int q = 0; q < 4; ++q) {
                float fu[8];
                bf8_to_f32(Ub + (size_t)(wid * 4 + q) * 1536 + kk, fu);  // broadcast
                ushort h[8] __attribute__((aligned(16)));
                #pragma unroll
                for (int e = 0; e < 8; ++e)
                    h[e] = f2bf(fmaxf(fu[e] + fv[e], 0.f));
                bf16x8 av = *(bf16x8*)h;
                acc[q] = __builtin_amdgcn_mfma_f32_16x16x32_bf16(av, bv, acc[q], 0, 0, 0);
            }
        }

        // D layout: col = fr (logit), pair-in-frag = kg*4 + jr
        if (fr < 10) {
            const float bias = b2r[fr];
            #pragma unroll
            for (int q = 0; q < 4; ++q) {
                const int i = i0 + wid * 4 + q;
                #pragma unroll
                for (int jr = 0; jr < 4; ++jr) {
                    const int j = j0 + kg * 4 + jr;
                    if (j > i) {
                        int p = i * 63 - i * (i - 1) / 2 + (j - i - 1);
                        rlog[((size_t)(b * NPAIR + p)) * 10 + fr] = acc[q][jr] + bias;
                    }
                }
            }
        }
    } else {
        // ---- entity logits ----
        const int rbase = (bid - 160) * 64 + wid * 16;
        f32x4 acc = {};
        #pragma unroll
        for (int c = 0; c < 12; ++c) {
            const int kk = c * 32 + kg * 8;
            bf16x8 av = *(const bf16x8*)(H1 + (size_t)(rbase + fr) * 384 + kk);
            bf16x8 bv = *(const bf16x8*)(W2et + fr * 384 + kk);
            acc = __builtin_amdgcn_mfma_f32_16x16x32_bf16(av, bv, acc, 0, 0, 0);
        }
        if (fr < 9) {
            const float bias = b2e[fr];
            #pragma unroll
            for (int j = 0; j < 4; ++j)
                elog[(size_t)(rbase + kg * 4 + j) * 9 + fr] = acc[j] + bias;
        }
    }
}

// ---------------------------------------------------------------------------
extern "C" void kernel_launch(void* const* d_in, const int* in_sizes, int n_in,
                              void* d_out, int out_size, void* d_ws, size_t ws_size,
                              hipStream_t stream)
{
    const float* seq   = (const float*)d_in[0];
    const int*   spans = (const int*)d_in[2];
    const float* W1e   = (const float*)d_in[3];
    const float* b1e   = (const float*)d_in[4];
    const float* W2e   = (const float*)d_in[5];
    const float* b2e   = (const float*)d_in[6];
    const float* W1r   = (const float*)d_in[7];
    const float* b1r   = (const float*)d_in[8];
    const float* W2r   = (const float*)d_in[9];
    const float* b2r   = (const float*)d_in[10];

    float* out  = (float*)d_out;
    float* elog = out;
    float* erep = out + 73728;
    float* rlog = out + 73728 + 786432;

    // ws layout (all rewritten every launch; poison-safe); seq_bf deleted.
    char* ws = (char*)d_ws;
    ushort* W1et    = (ushort*)(ws + 0);              //    589,824
    ushort* W1rt    = (ushort*)(ws + 589824);         //  2,359,296
    ushort* erep_bf = (ushort*)(ws + 2949120);        //  1,572,864
    ushort* H1bf    = (ushort*)(ws + 4521984);        //  6,291,456
    ushort* W2rt    = (ushort*)(ws + 10813440);       //     24,576
    ushort* W2et    = (ushort*)(ws + 10838016);       //     12,288
    float*  b1r_ext = (float*) (ws + 10850304);       //      6,144
    ushort* UVbf    = (ushort*)(ws + 10856448);       //  3,145,728
    // total 14,002,176 B

    // K_A: all prep (span, transposes, small weights)
    prep_all_k<<<2542, 256, 0, stream>>>(seq, spans, W1e, W1r, W2e, W2r, b1r,
                                         erep, erep_bf, W1et, W1rt, W2et, W2rt,
                                         b1r_ext);
    // K_B: both GEMMs fused (independent): H1bf (A = f32 seq direct) + UVbf
    gemm2_k<<<576, 256, 0, stream>>>(seq, W1et, b1e, H1bf,
                                     erep_bf, W1rt, b1r_ext, UVbf);
    // K_C: relation_logits + entity_logits fused (independent consumers)
    post_k<<<288, 256, 0, stream>>>(UVbf, W2rt, b2r, rlog,
                                    H1bf, W2et, b2e, elog);
}